// Round 1
// baseline (693.666 us; speedup 1.0000x reference)
//
#include <hip/hip_runtime.h>

#define BATCH 4096
#define SEQ   2048

// Pre-scale constants: sigmoid(x) = rcp(1 + exp2(-x*log2e)); tanh(x) = 2*rcp(1+exp2(-2x*log2e)) - 1
#define NL2E  (-1.44269504088896340736f)   // -log2(e)
#define N2L2E (-2.88539008177792681472f)   // -2*log2(e)

__device__ __forceinline__ float fast_rcp(float x) { return __builtin_amdgcn_rcpf(x); }
__device__ __forceinline__ float fast_exp2(float x) { return __builtin_amdgcn_exp2f(x); }

__global__ __launch_bounds__(64, 1) void pew_kernel(
    const float* __restrict__ x,
    const float* __restrict__ W1, const float* __restrict__ U1,
    const float* __restrict__ V1, const float* __restrict__ b1,
    const float* __restrict__ W2, const float* __restrict__ U2,
    const float* __restrict__ V2, const float* __restrict__ b2,
    const float* __restrict__ fc_w, const float* __restrict__ fc_b,
    float* __restrict__ out)
{
    const int b = blockIdx.x * blockDim.x + threadIdx.x;
    if (b >= BATCH) return;

    // ---- load + pre-scale weights into registers (uniform -> scalar loads) ----
    float wg1[4], ug1[4], vg1[4][4], bg1[4];
    float wg2[4], ug2[4], vg2[4][4], bg2[4];
#pragma unroll
    for (int j = 0; j < 4; ++j) {
        const float sc = (j == 2) ? N2L2E : NL2E;   // gate 2 (g) is tanh
        wg1[j] = W1[j] * sc;  ug1[j] = U1[j] * sc;  bg1[j] = b1[j] * sc;
        wg2[j] = W2[j] * sc;  ug2[j] = U2[j] * sc;  bg2[j] = b2[j] * sc;
#pragma unroll
        for (int k = 0; k < 4; ++k) {
            vg1[k][j] = V1[k * 4 + j] * sc;
            vg2[k][j] = V2[k * 4 + j] * sc;
        }
    }
    const float fw = fc_w[0];
    const float fb = fc_b[0];

    float h1 = 0.f, c1 = 0.f, h2 = 0.f, c2 = 0.f;

    const float4* __restrict__ xq = (const float4*)(x + (size_t)b * (SEQ * 5));
    float4* __restrict__ oq = (float4*)(out + (size_t)b * SEQ);

    // LSTM cell step: inputs pre-scaled weights; returns new h (updates c in place).
    auto cell = [&](float in, float w0, float w1v, float w2v, float w3v,
                    const float (&wg)[4], const float (&ug)[4],
                    const float (&vg)[4][4], const float (&bg)[4],
                    float& h, float& c) {
        float a[4];
#pragma unroll
        for (int j = 0; j < 4; ++j) {
            float t = fmaf(in, wg[j], bg[j]);
            t = fmaf(h, ug[j], t);
            t = fmaf(w0, vg[0][j], t);
            t = fmaf(w1v, vg[1][j], t);
            t = fmaf(w2v, vg[2][j], t);
            t = fmaf(w3v, vg[3][j], t);
            a[j] = t;   // = -log2e * gate_pre  (or -2log2e for g)
        }
        const float ig = fast_rcp(1.f + fast_exp2(a[0]));
        const float fg = fast_rcp(1.f + fast_exp2(a[1]));
        const float gg = fmaf(2.f, fast_rcp(1.f + fast_exp2(a[2])), -1.f);
        const float og = fast_rcp(1.f + fast_exp2(a[3]));
        c = fmaf(fg, c, ig * gg);
        const float th = fmaf(2.f, fast_rcp(1.f + fast_exp2(c * N2L2E)), -1.f);
        h = og * th;
    };

    // ---- register double-buffer: chunk = 4 timesteps = 20 floats = 5x float4 ----
    float4 n0 = xq[0], n1 = xq[1], n2 = xq[2], n3 = xq[3], n4 = xq[4];

    for (int tc = 0; tc < SEQ / 4; ++tc) {
        const float4 q0 = n0, q1 = n1, q2 = n2, q3 = n3, q4 = n4;
        if (tc + 1 < SEQ / 4) {                 // issue next-chunk loads early
            const int nb = (tc + 1) * 5;
            n0 = xq[nb + 0]; n1 = xq[nb + 1]; n2 = xq[nb + 2];
            n3 = xq[nb + 3]; n4 = xq[nb + 4];
        }

        float xs[20];
        xs[0]=q0.x;  xs[1]=q0.y;  xs[2]=q0.z;  xs[3]=q0.w;  xs[4]=q1.x;
        xs[5]=q1.y;  xs[6]=q1.z;  xs[7]=q1.w;  xs[8]=q2.x;  xs[9]=q2.y;
        xs[10]=q2.z; xs[11]=q2.w; xs[12]=q3.x; xs[13]=q3.y; xs[14]=q3.z;
        xs[15]=q3.w; xs[16]=q4.x; xs[17]=q4.y; xs[18]=q4.z; xs[19]=q4.w;

        float res[4];
#pragma unroll
        for (int s = 0; s < 4; ++s) {
            const float w0 = xs[s * 5 + 0];
            const float w1v = xs[s * 5 + 1];
            const float w2v = xs[s * 5 + 2];
            const float w3v = xs[s * 5 + 3];
            const float p  = xs[s * 5 + 4];

            cell(p,  w0, w1v, w2v, w3v, wg1, ug1, vg1, bg1, h1, c1);  // layer 1
            cell(h1, w0, w1v, w2v, w3v, wg2, ug2, vg2, bg2, h2, c2);  // layer 2
            res[s] = fmaf(h2, fw, fb);
        }
        oq[tc] = make_float4(res[0], res[1], res[2], res[3]);
    }
}

extern "C" void kernel_launch(void* const* d_in, const int* in_sizes, int n_in,
                              void* d_out, int out_size, void* d_ws, size_t ws_size,
                              hipStream_t stream) {
    (void)in_sizes; (void)n_in; (void)out_size; (void)d_ws; (void)ws_size;
    const float* x    = (const float*)d_in[0];
    const float* W1   = (const float*)d_in[1];
    const float* U1   = (const float*)d_in[2];
    const float* V1   = (const float*)d_in[3];
    const float* b1   = (const float*)d_in[4];
    const float* W2   = (const float*)d_in[5];
    const float* U2   = (const float*)d_in[6];
    const float* V2   = (const float*)d_in[7];
    const float* b2   = (const float*)d_in[8];
    const float* fc_w = (const float*)d_in[9];
    const float* fc_b = (const float*)d_in[10];
    float* out = (float*)d_out;

    pew_kernel<<<dim3(BATCH / 64), dim3(64), 0, stream>>>(
        x, W1, U1, V1, b1, W2, U2, V2, b2, fc_w, fc_b, out);
}

// Round 2
// 548.403 us; speedup vs baseline: 1.2649x; 1.2649x over previous
//
#include <hip/hip_runtime.h>

#define BATCH 4096
#define SEQ   2048

// Pre-scale: sigmoid(x) = rcp(1 + exp2(-x*log2e)); tanh(x) = 2*rcp(1+exp2(-2x*log2e)) - 1
#define NL2E  (-1.44269504088896340736f)   // -log2(e)
#define N2L2E (-2.88539008177792681472f)   // -2*log2(e)

__device__ __forceinline__ float fexp2(float x) { return __builtin_amdgcn_exp2f(x); }
__device__ __forceinline__ float frcp(float x)  { return __builtin_amdgcn_rcpf(x); }

// quad_perm broadcast: PAT = l | l<<2 | l<<4 | l<<6 for source lane l in quad.
template <int PAT>
__device__ __forceinline__ float qb(float v) {
    return __int_as_float(
        __builtin_amdgcn_mov_dpp(__float_as_int(v), PAT, 0xf, 0xf, false));
}

__global__ __launch_bounds__(64, 1) void pew4(
    const float* __restrict__ x,
    const float* __restrict__ W1, const float* __restrict__ U1,
    const float* __restrict__ V1, const float* __restrict__ b1,
    const float* __restrict__ W2, const float* __restrict__ U2,
    const float* __restrict__ V2, const float* __restrict__ b2,
    const float* __restrict__ fc_w, const float* __restrict__ fc_b,
    float* __restrict__ out)
{
    const int tid = threadIdx.x;
    const int g   = tid & 3;                          // this lane's gate (i,f,g,o)
    const int row = (blockIdx.x * 64 + tid) >> 2;     // 16 rows per wave

    // ---- per-lane pre-scaled weights (gate g only) ----
    const float sc = (g == 2) ? N2L2E : NL2E;         // g-gate is tanh
    const float w1 = W1[g] * sc, u1 = U1[g] * sc, bb1 = b1[g] * sc;
    const float v10 = V1[0*4+g]*sc, v11 = V1[1*4+g]*sc,
                v12 = V1[2*4+g]*sc, v13 = V1[3*4+g]*sc;
    const float w2 = W2[g] * sc, u2 = U2[g] * sc, bb2 = b2[g] * sc;
    const float v20 = V2[0*4+g]*sc, v21 = V2[1*4+g]*sc,
                v22 = V2[2*4+g]*sc, v23 = V2[3*4+g]*sc;
    // activation finisher: sigmoid lanes act=r, tanh lane act=2r-1
    const float sA = (g == 2) ? 2.f : 1.f;
    const float oA = (g == 2) ? -1.f : 0.f;
    const float fw = fc_w[0], fb = fc_b[0];

    float h1 = 0.f, c1 = 0.f, h2 = 0.f, c2 = 0.f;

    const float4* __restrict__ xq = (const float4*)(x + (size_t)row * (SEQ * 5));
    float4* __restrict__ oq = (float4*)(out + (size_t)row * SEQ);

    // register double-buffer: 4 timesteps = 20 floats = 5x float4 (quad-redundant)
    float4 n0 = xq[0], n1 = xq[1], n2 = xq[2], n3 = xq[3], n4 = xq[4];

    for (int tcb = 0; tcb < SEQ / 4; ++tcb) {
        const float4 q0 = n0, q1 = n1, q2 = n2, q3 = n3, q4 = n4;
        if (tcb + 1 < SEQ / 4) {
            const int nb = (tcb + 1) * 5;
            n0 = xq[nb+0]; n1 = xq[nb+1]; n2 = xq[nb+2]; n3 = xq[nb+3]; n4 = xq[nb+4];
        }

        float xs[20];
        xs[0]=q0.x;  xs[1]=q0.y;  xs[2]=q0.z;  xs[3]=q0.w;  xs[4]=q1.x;
        xs[5]=q1.y;  xs[6]=q1.z;  xs[7]=q1.w;  xs[8]=q2.x;  xs[9]=q2.y;
        xs[10]=q2.z; xs[11]=q2.w; xs[12]=q3.x; xs[13]=q3.y; xs[14]=q3.z;
        xs[15]=q3.w; xs[16]=q4.x; xs[17]=q4.y; xs[18]=q4.z; xs[19]=q4.w;

        float res[4];
#pragma unroll
        for (int s = 0; s < 4; ++s) {
            const float w0 = xs[5*s+0], wA = xs[5*s+1], wB = xs[5*s+2],
                        wC = xs[5*s+3], p  = xs[5*s+4];

            // ---- layer 1: this lane's gate pre-activation ----
            float a = bb1;
            a = fmaf(p,  w1,  a);
            a = fmaf(h1, u1,  a);
            a = fmaf(w0, v10, a); a = fmaf(wA, v11, a);
            a = fmaf(wB, v12, a); a = fmaf(wC, v13, a);
            float r   = frcp(1.f + fexp2(a));
            float act = fmaf(sA, r, oA);
            // share gates within quad (VALU-speed DPP broadcast)
            float gi = qb<0x00>(act), gf = qb<0x55>(act),
                  gg = qb<0xAA>(act), go = qb<0xFF>(act);
            c1 = fmaf(gf, c1, gi * gg);
            float th = fmaf(2.f, frcp(1.f + fexp2(c1 * N2L2E)), -1.f);
            h1 = go * th;

            // ---- layer 2 ----
            a = bb2;
            a = fmaf(h1, w2,  a);
            a = fmaf(h2, u2,  a);
            a = fmaf(w0, v20, a); a = fmaf(wA, v21, a);
            a = fmaf(wB, v22, a); a = fmaf(wC, v23, a);
            r   = frcp(1.f + fexp2(a));
            act = fmaf(sA, r, oA);
            gi = qb<0x00>(act); gf = qb<0x55>(act);
            gg = qb<0xAA>(act); go = qb<0xFF>(act);
            c2 = fmaf(gf, c2, gi * gg);
            th = fmaf(2.f, frcp(1.f + fexp2(c2 * N2L2E)), -1.f);
            h2 = go * th;

            res[s] = fmaf(h2, fw, fb);
        }
        if (g == 0) oq[tcb] = make_float4(res[0], res[1], res[2], res[3]);
    }
}

extern "C" void kernel_launch(void* const* d_in, const int* in_sizes, int n_in,
                              void* d_out, int out_size, void* d_ws, size_t ws_size,
                              hipStream_t stream) {
    (void)in_sizes; (void)n_in; (void)out_size; (void)d_ws; (void)ws_size;
    const float* x    = (const float*)d_in[0];
    const float* W1   = (const float*)d_in[1];
    const float* U1   = (const float*)d_in[2];
    const float* V1   = (const float*)d_in[3];
    const float* b1   = (const float*)d_in[4];
    const float* W2   = (const float*)d_in[5];
    const float* U2   = (const float*)d_in[6];
    const float* V2   = (const float*)d_in[7];
    const float* b2   = (const float*)d_in[8];
    const float* fc_w = (const float*)d_in[9];
    const float* fc_b = (const float*)d_in[10];
    float* out = (float*)d_out;

    // 4096 rows x 4 gate-lanes = 16384 threads = 256 waves (one per CU)
    pew4<<<dim3(BATCH * 4 / 64), dim3(64), 0, stream>>>(
        x, W1, U1, V1, b1, W2, U2, V2, b2, fc_w, fc_b, out);
}